// Round 7
// baseline (485.485 us; speedup 1.0000x reference)
//
#include <hip/hip_runtime.h>
#include <hip/hip_bf16.h>

#define B 4
#define H 480
#define W 640
#define HW (H*W)
#define NKP 1024
#define THRESH 0.005f
#define CAP 16384
#define NCOL (B*NKP)
#define KTOT 704

typedef __attribute__((ext_vector_type(4))) short s4v;
typedef __attribute__((ext_vector_type(8))) short s8v;
typedef __attribute__((ext_vector_type(4))) float f4v;

__device__ __forceinline__ short f2bf(float f) {
    __hip_bfloat16 h = __float2bfloat16(f);
    return *(short*)&h;
}
__device__ __forceinline__ float bf2f(unsigned short u) {
    return __uint_as_float(((unsigned)u) << 16);
}

// device-scope producer/consumer handshake (cross-XCD safe: agent scope
// release writes back L2, acquire invalidates; __syncthreads drains vmcnt
// so all block stores are in L2 before the release).
__device__ __forceinline__ void rel_add(int* p) {
    __syncthreads();
    if (threadIdx.x == 0)
        __hip_atomic_fetch_add(p, 1, __ATOMIC_RELEASE, __HIP_MEMORY_SCOPE_AGENT);
}
__device__ __forceinline__ void acq_wait(int* p, int val) {
    if (threadIdx.x == 0)
        while (__hip_atomic_load(p, __ATOMIC_ACQUIRE, __HIP_MEMORY_SCOPE_AGENT) < val)
            __builtin_amdgcn_s_sleep(8);
    __syncthreads();
}

// ===================== k1: fuse weights + nms1 + 4 transposes =====================

template <int CMAP>
__device__ void transpose_role(const float* __restrict__ in, unsigned short* __restrict__ out,
                               int h, int w, int idx, char* smem) {
    float* Ts = (float*)smem;   // [64][65]
    int lx = threadIdx.x & 63, lr = threadIdx.x >> 6;
    int ntx = (w + 63) >> 6;
    int xt = idx % ntx;
    int rem = idx / ntx;
    int y = rem % h;
    int bz = rem / h;                 // b*(CMAP/64) + ctile
    int b = bz / (CMAP / 64);
    int c0 = (bz % (CMAP / 64)) * 64;
    int x0 = xt * 64;
    int x = x0 + lx;
    #pragma unroll
    for (int i = 0; i < 16; ++i) {
        int cl = lr + i * 4;
        float v = 0.0f;
        if (x < w) v = in[(((size_t)(b * CMAP + c0 + cl)) * h + y) * w + x];
        Ts[cl * 65 + lx] = v;
    }
    __syncthreads();
    #pragma unroll
    for (int j = 0; j < 16; ++j) {
        int xl = lr + j * 4;
        int xg = x0 + xl;
        if (xg < w)
            out[((size_t)(b * h + y) * w + xg) * CMAP + c0 + lx] =
                (unsigned short)f2bf(Ts[lx * 65 + xl]);
    }
}

__global__ __launch_bounds__(256) void k1(
    const float* __restrict__ merge_w, const float* __restrict__ merge_b,
    const float* __restrict__ lin0_w, const float* __restrict__ lin0_b,
    const float* __restrict__ lin1_w, const float* __restrict__ lin1_b,
    const float* __restrict__ lin2_w, const float* __restrict__ lin2_b,
    const float* __restrict__ scores,
    const float* __restrict__ d1, const float* __restrict__ d2,
    const float* __restrict__ cDa, const float* __restrict__ d4,
    float* __restrict__ Mw, float* __restrict__ biasf, int* __restrict__ cnt,
    int* __restrict__ done, unsigned char* __restrict__ M0,
    unsigned short* __restrict__ T1, unsigned short* __restrict__ T2,
    unsigned short* __restrict__ T3, unsigned short* __restrict__ T4)
{
    __shared__ __align__(16) char smem[16896];
    int bid = blockIdx.x;
    if (bid < 704) {
        int e = bid * 256 + threadIdx.x;
        int o = e / KTOT, j = e - o * KTOT;
        float acc = 0.0f;
        if (j < 64) {
            for (int k = 0; k < 64; ++k) acc += merge_w[o * KTOT + k] * lin2_w[k * 64 + j];
        } else if (j < 192) {
            int jj = j - 64;
            for (int k = 0; k < 128; ++k) acc += merge_w[o * KTOT + 64 + k] * lin1_w[k * 128 + jj];
        } else if (j < 448) {
            acc = merge_w[o * KTOT + j];
        } else {
            int jj = j - 448;
            for (int k = 0; k < 256; ++k) acc += merge_w[o * KTOT + 448 + k] * lin0_w[k * 256 + jj];
        }
        Mw[o * KTOT + j] = acc;
    } else if (bid == 704) {
        int o = threadIdx.x;
        if (o < 4) cnt[o * 64] = 0;
        if (o == 4) done[0] = 0;
        if (o == 5) done[64] = 0;
        float acc = merge_b[o];
        for (int k = 0; k < 64; ++k)  acc += merge_w[o * KTOT + k] * lin2_b[k];
        for (int k = 0; k < 128; ++k) acc += merge_w[o * KTOT + 64 + k] * lin1_b[k];
        for (int k = 0; k < 256; ++k) acc += merge_w[o * KTOT + 448 + k] * lin0_b[k];
        biasf[o] = acc;
    } else if (bid < 1905) {
        // nms1: mask0 = (S == pool9(S))
        float* tile = (float*)smem;          // 40*40
        float* hm   = (float*)(smem + 6400); // 40*32
        int b2 = bid - 705;
        int bx = b2 % 20, by = (b2 / 20) % 15, bz = b2 / 300;
        int x0 = bx * 32, y0 = by * 32;
        const float* sp = scores + bz * HW;
        for (int t = threadIdx.x; t < 1600; t += 256) {
            int ly = t / 40, lx = t - ly * 40;
            int gy = y0 - 4 + ly, gx = x0 - 4 + lx;
            tile[ly * 40 + lx] = (gy >= 0 && gy < H && gx >= 0 && gx < W) ? sp[gy * W + gx] : -INFINITY;
        }
        __syncthreads();
        for (int t = threadIdx.x; t < 1280; t += 256) {
            int ly = t >> 5, lx = t & 31;
            float m = tile[ly * 40 + lx];
            #pragma unroll
            for (int d = 1; d < 9; ++d) m = fmaxf(m, tile[ly * 40 + lx + d]);
            hm[ly * 32 + lx] = m;
        }
        __syncthreads();
        for (int t = threadIdx.x; t < 1024; t += 256) {
            int ly = t >> 5, lx = t & 31;
            float m = hm[ly * 32 + lx];
            #pragma unroll
            for (int d = 1; d < 9; ++d) m = fmaxf(m, hm[(ly + d) * 32 + lx]);
            float s = tile[(ly + 4) * 40 + lx + 4];
            M0[bz * HW + (y0 + ly) * W + x0 + lx] = (s == m) ? 1 : 0;
        }
    } else if (bid < 6705) {
        transpose_role<64>(d1, T1, 240, 320, bid - 1905, smem);
    } else if (bid < 9585) {
        transpose_role<128>(d2, T2, 120, 160, bid - 6705, smem);
    } else if (bid < 11505) {
        transpose_role<256>(cDa, T3, 60, 80, bid - 9585, smem);
    } else {
        transpose_role<256>(d4, T4, 30, 40, bid - 11505, smem);
    }
}

// ===================== NMS recovery iteration (shared by k2 / k3) =====================
// maskOut = maskIn | newmax(Z), Z = pool9(maskIn)>0 ? -1 : S. 32x32 out, halo 8.
template <bool COMPACT>
__device__ void iter_role(const float* __restrict__ scores, const unsigned char* __restrict__ maskIn,
                          unsigned char* __restrict__ maskOut, unsigned long long* __restrict__ cand,
                          int* __restrict__ cnt, int bx, int by, int bz, char* smem,
                          int* lcnt, int* gbase) {
    int*   Mi = (int*)smem;                 // 48*48
    int*   Ti = (int*)(smem + 9216);        // 48*40
    float* Sm = (float*)(smem + 16896);     // 40*40
    float* Zm = (float*)(smem + 23296);     // 40*40
    float* Tf = (float*)(smem + 29696);     // 40*32
    int x0 = bx * 32, y0 = by * 32;
    const float* sp = scores + bz * HW;
    const unsigned char* mp = maskIn + bz * HW;
    if (COMPACT && threadIdx.x == 0) *lcnt = 0;
    for (int t = threadIdx.x; t < 2304; t += 256) {
        int ly = t / 48, lx = t - ly * 48;
        int gy = y0 - 8 + ly, gx = x0 - 8 + lx;
        Mi[t] = (gy >= 0 && gy < H && gx >= 0 && gx < W) ? (int)mp[gy * W + gx] : 0;
    }
    for (int t = threadIdx.x; t < 1600; t += 256) {
        int ly = t / 40, lx = t - ly * 40;
        int gy = y0 - 4 + ly, gx = x0 - 4 + lx;
        Sm[t] = (gy >= 0 && gy < H && gx >= 0 && gx < W) ? sp[gy * W + gx] : -1.0f;
    }
    __syncthreads();
    for (int t = threadIdx.x; t < 1920; t += 256) {
        int i = t / 40, c = t - i * 40;
        int m = Mi[i * 48 + c];
        #pragma unroll
        for (int d = 1; d < 9; ++d) m |= Mi[i * 48 + c + d];
        Ti[i * 40 + c] = m;
    }
    __syncthreads();
    for (int t = threadIdx.x; t < 1600; t += 256) {
        int i = t / 40, c = t - i * 40;
        int m = Ti[i * 40 + c];
        #pragma unroll
        for (int d = 1; d < 9; ++d) m |= Ti[(i + d) * 40 + c];
        Zm[t] = m ? -1.0f : Sm[t];
    }
    __syncthreads();
    for (int t = threadIdx.x; t < 1280; t += 256) {
        int i = t >> 5, c = t & 31;
        float m = Zm[i * 40 + c];
        #pragma unroll
        for (int d = 1; d < 9; ++d) m = fmaxf(m, Zm[i * 40 + c + d]);
        Tf[i * 32 + c] = m;
    }
    __syncthreads();
    unsigned long long keys[4];
    int nl = 0;
    #pragma unroll
    for (int q = 0; q < 4; ++q) {
        int t = threadIdx.x + q * 256;
        int r = t >> 5, c = t & 31;
        float m = Tf[r * 32 + c];
        #pragma unroll
        for (int d = 1; d < 9; ++d) m = fmaxf(m, Tf[(r + d) * 32 + c]);
        float Zc = Zm[(r + 4) * 40 + c + 4];
        bool nm = (Zc == m) && (Zc >= 0.0f);
        int m1 = Mi[(r + 8) * 48 + c + 8] | (nm ? 1 : 0);
        int gy = y0 + r, gx = x0 + c;
        if (!COMPACT) {
            maskOut[bz * HW + gy * W + gx] = (unsigned char)m1;
        } else {
            float sc = Sm[(r + 4) * 40 + c + 4];
            if (m1 && gy >= 4 && gy < H - 4 && gx >= 4 && gx < W - 4 && sc > THRESH) {
                unsigned rr = (unsigned)(gy * W + gx);
                unsigned bits = __float_as_uint(sc) | 0x80000000u;
                keys[nl++] = ((unsigned long long)bits << 32) |
                             (unsigned long long)(0xFFFFFFFFu - rr);
            }
        }
    }
    if (COMPACT) {
        int lpos = 0;
        if (nl) lpos = atomicAdd(lcnt, nl);
        __syncthreads();
        if (threadIdx.x == 0) *gbase = (*lcnt > 0) ? atomicAdd(&cnt[bz * 64], *lcnt) : 0;
        __syncthreads();
        for (int j = 0; j < nl; ++j) {
            int p = *gbase + lpos + j;
            if (p < CAP) cand[(size_t)bz * CAP + p] = keys[j];
        }
    }
}

__global__ __launch_bounds__(256) void k2(const float* __restrict__ scores,
                                          const unsigned char* __restrict__ M0,
                                          unsigned char* __restrict__ M1) {
    __shared__ __align__(16) char smem[34816];
    __shared__ int sl, sg;
    int b2 = blockIdx.x;
    iter_role<false>(scores, M0, M1, nullptr, nullptr,
                     b2 % 20, (b2 / 20) % 15, b2 / 300, smem, &sl, &sg);
}

// ===================== k3: iterB+compact (1200 blocks) + topk (4 spin blocks) =====================

__device__ void topk_role(const unsigned long long* __restrict__ cand, const int* __restrict__ cnt,
                          float* __restrict__ out, int* __restrict__ fidx, int b,
                          char* smem, int* si) {
    int* hist = (int*)smem;                                       // 2048 ints
    unsigned long long* buf = (unsigned long long*)(smem + 8192); // 4096 u64
    int tid = threadIdx.x;
    int m = cnt[b * 64]; if (m > CAP) m = CAP;
    const unsigned long long* cb = cand + (size_t)b * CAP;
    int target = (m < 1024) ? m : 1024;
    for (int t = tid; t < 2048; t += 256) hist[t] = 0;
    if (tid == 0) { si[0] = 0; si[1] = 2048; si[2] = 0; si[3] = 0; }
    __syncthreads();
    // pass 1: bits [63:53], wave-aggregated
    for (int i = tid; i < m; i += 256) {
        int bin = (int)(cb[i] >> 53) & 0x7FF;
        int first = __builtin_amdgcn_readfirstlane(bin);
        unsigned long long same = __ballot(bin == first);
        if (same == ~0ULL) { if ((tid & 63) == 0) atomicAdd(&hist[first], 64); }
        else atomicAdd(&hist[bin], 1);
    }
    __syncthreads();
    for (int d = 1; d < 2048; d <<= 1) {
        int v[8];
        #pragma unroll
        for (int j = 0; j < 8; ++j) { int t = tid + j * 256; v[j] = hist[t] + ((t + d < 2048) ? hist[t + d] : 0); }
        __syncthreads();
        #pragma unroll
        for (int j = 0; j < 8; ++j) hist[tid + j * 256] = v[j];
        __syncthreads();
    }
    if (target > 0)
        for (int t = tid; t < 2048; t += 256) {
            int c = hist[t], cn = (t < 2047) ? hist[t + 1] : 0;
            if (c >= target && cn < target) { si[1] = t; si[3] = cn; }
        }
    __syncthreads();
    int piv1 = si[1], target2 = target - si[3];
    for (int t = tid; t < 2048; t += 256) hist[t] = 0;
    __syncthreads();
    for (int i = tid; i < m; i += 256) {
        unsigned long long k = cb[i];
        if (((int)(k >> 53) & 0x7FF) == piv1) atomicAdd(&hist[(int)(k >> 42) & 0x7FF], 1);
    }
    __syncthreads();
    for (int d = 1; d < 2048; d <<= 1) {
        int v[8];
        #pragma unroll
        for (int j = 0; j < 8; ++j) { int t = tid + j * 256; v[j] = hist[t] + ((t + d < 2048) ? hist[t + d] : 0); }
        __syncthreads();
        #pragma unroll
        for (int j = 0; j < 8; ++j) hist[tid + j * 256] = v[j];
        __syncthreads();
    }
    if (target > 0)
        for (int t = tid; t < 2048; t += 256) {
            int c = hist[t], cn = (t < 2047) ? hist[t + 1] : 0;
            if (c >= target2 && cn < target2) si[2] = t;
        }
    __syncthreads();
    int piv2 = si[2];
    for (int i = tid; i < m; i += 256) {
        unsigned long long k = cb[i];
        int b1 = (int)(k >> 53) & 0x7FF;
        bool sel = (target > 0) &&
                   (b1 > piv1 || (b1 == piv1 && (((int)(k >> 42) & 0x7FF) >= piv2)));
        if (sel) { int p = atomicAdd(&si[0], 1); if (p < 4096) buf[p] = k; }
    }
    __syncthreads();
    int sc_ = si[0]; if (sc_ > 4096) sc_ = 4096;
    for (int n = tid; n < 1024; n += 256)
        if (n >= target) {
            int bn = b * NKP + n;
            out[bn * 2 + 0] = 0.0f;
            out[bn * 2 + 1] = 0.0f;
            out[B * NKP * 2 + bn] = -1.0f;
            fidx[bn] = 0;
        }
    // rank-sort (keys unique -> unique ranks)
    for (int c0 = 0; c0 < 4096; c0 += 1024) {
        if (c0 >= sc_) break;
        unsigned long long k[4]; int r[4] = {0, 0, 0, 0};
        #pragma unroll
        for (int q = 0; q < 4; ++q) { int i = c0 + q * 256 + tid; k[q] = (i < sc_) ? buf[i] : 0ULL; }
        for (int j = 0; j < sc_; ++j) {
            unsigned long long v = buf[j];
            r[0] += (v > k[0]); r[1] += (v > k[1]); r[2] += (v > k[2]); r[3] += (v > k[3]);
        }
        #pragma unroll
        for (int q = 0; q < 4; ++q) {
            int i = c0 + q * 256 + tid;
            if (i < sc_ && r[q] < target) {
                unsigned long long kk = k[q];
                unsigned ord = (unsigned)(kk >> 32);
                float sc = __uint_as_float(ord ^ 0x80000000u);
                unsigned idx = 0xFFFFFFFFu - (unsigned)(kk & 0xFFFFFFFFu);
                int bn = b * NKP + r[q];
                out[bn * 2 + 0] = (float)(idx % W);
                out[bn * 2 + 1] = (float)(idx / W);
                out[B * NKP * 2 + bn] = sc;
                fidx[bn] = (int)idx;
            }
        }
    }
}

__global__ __launch_bounds__(256) void k3(const float* __restrict__ scores,
                                          const unsigned char* __restrict__ M1,
                                          unsigned long long* __restrict__ cand,
                                          int* __restrict__ cnt, int* __restrict__ done,
                                          float* __restrict__ out, int* __restrict__ fidx) {
    __shared__ __align__(16) char smem[40960];
    __shared__ int si[6];
    if (blockIdx.x < 1200) {
        int b2 = blockIdx.x;
        iter_role<true>(scores, M1, nullptr, cand, cnt,
                        b2 % 20, (b2 / 20) % 15, b2 / 300, smem, &si[4], &si[5]);
        rel_add(done);
    } else {
        acq_wait(done, 1200);
        topk_role(cand, cnt, out, fidx, blockIdx.x - 1200, smem, si);
    }
}

// ===================== k4: sample (4096 blocks) + gemm (256 spin blocks) =====================

__device__ void sample_role(const unsigned short* __restrict__ T1, const unsigned short* __restrict__ T2,
                            const unsigned short* __restrict__ T3, const unsigned short* __restrict__ T4,
                            const int* __restrict__ fidx, unsigned short* __restrict__ X, char* smem) {
    float* wred  = (float*)smem;        // [4 waves][4 segs]
    float* norms = (float*)smem + 16;   // [4]
    int col = blockIdx.x, b = col >> 10, tid = threadIdx.x;
    int idx = fidx[col];
    float kx = (float)(idx % W), ky = (float)(idx / W);
    float vv[3]; int sg[3];
    float part[4] = {0.f, 0.f, 0.f, 0.f};
    #pragma unroll
    for (int q = 0; q < 3; ++q) {
        int c = tid + q * 256;
        bool valid = (q < 2) || (tid < 192);
        vv[q] = 0.f; sg[q] = 0;
        if (!valid) continue;
        const unsigned short* T; int h, w, s, cl, C, seg;
        if (c < 64)       { T = T1; h = 240; w = 320; s = 2;  cl = c;       C = 64;  seg = 0; }
        else if (c < 192) { T = T2; h = 120; w = 160; s = 4;  cl = c - 64;  C = 128; seg = 1; }
        else if (c < 448) { T = T3; h = 60;  w = 80;  s = 8;  cl = c - 192; C = 256; seg = 2; }
        else              { T = T4; h = 30;  w = 40;  s = 16; cl = c - 448; C = 256; seg = 3; }
        float kxs = (kx - (float)s * 0.5f) + 0.5f;
        float kys = (ky - (float)s * 0.5f) + 0.5f;
        float gx = kxs / (float)(w * s - 1) * 2.0f - 1.0f;
        float gy = kys / (float)(h * s - 1) * 2.0f - 1.0f;
        float x = (gx + 1.0f) * 0.5f * (float)(w - 1);
        float y = (gy + 1.0f) * 0.5f * (float)(h - 1);
        float x0f = floorf(x), y0f = floorf(y);
        int x0 = (int)x0f, y0 = (int)y0f;
        float wx1 = x - x0f, wy1 = y - y0f, wx0 = 1.f - wx1, wy0 = 1.f - wy1;
        auto tap = [&](int xi, int yi) -> float {
            bool ok = (xi >= 0) && (xi < w) && (yi >= 0) && (yi < h);
            int xc = min(max(xi, 0), w - 1), yc = min(max(yi, 0), h - 1);
            unsigned short u = T[((size_t)(b * h + yc) * w + xc) * C + cl];
            return ok ? bf2f(u) : 0.f;
        };
        float v = tap(x0, y0) * (wx0 * wy0) + tap(x0 + 1, y0) * (wx1 * wy0) +
                  tap(x0, y0 + 1) * (wx0 * wy1) + tap(x0 + 1, y0 + 1) * (wx1 * wy1);
        vv[q] = v; sg[q] = seg; part[seg] += v * v;
    }
    int lane = tid & 63, wv = tid >> 6;
    #pragma unroll
    for (int s4 = 0; s4 < 4; ++s4) {
        float p = part[s4];
        #pragma unroll
        for (int off = 32; off > 0; off >>= 1) p += __shfl_down(p, off);
        if (lane == 0) wred[wv * 4 + s4] = p;
    }
    __syncthreads();
    if (tid < 4) {
        float ssum = wred[tid] + wred[4 + tid] + wred[8 + tid] + wred[12 + tid];
        norms[tid] = fmaxf(sqrtf(ssum), 1e-12f);
    }
    __syncthreads();
    #pragma unroll
    for (int q = 0; q < 3; ++q) {
        int c = tid + q * 256;
        bool valid = (q < 2) || (tid < 192);
        if (valid) X[(size_t)col * KTOT + c] = (unsigned short)f2bf(vv[q] / norms[sg[q]]);
    }
}

__device__ void gemm_role(const float* __restrict__ Mw, const unsigned short* __restrict__ X,
                          const float* __restrict__ biasf, float* __restrict__ out,
                          int bid2, char* smem) {
    short* As = (short*)smem;            // 64*68
    short* Bs = (short*)(smem + 8704);   // 64*68
    int tid = threadIdx.x;
    int lane = tid & 63, w = tid >> 6;
    int r = lane & 15, quad = lane >> 4;
    int rowBase = (bid2 >> 6) * 64, colBase = (bid2 & 63) * 64;
    int sm = tid >> 2, skq = (tid & 3) << 4;

    const float* pa = Mw + (size_t)(rowBase + sm) * KTOT + skq;
    const unsigned short* pb = X + (size_t)(colBase + sm) * KTOT + skq;
    float4 a0 = *(const float4*)(pa + 0), a1 = *(const float4*)(pa + 4);
    float4 a2 = *(const float4*)(pa + 8), a3 = *(const float4*)(pa + 12);
    s8v b01 = *(const s8v*)(pb);
    s8v b23 = *(const s8v*)(pb + 8);

    f4v acc[4];
    #pragma unroll
    for (int t = 0; t < 4; ++t) acc[t] = (f4v)0.0f;

    for (int kt = 0; kt < 11; ++kt) {
        __syncthreads();
        {
            s4v v0 = { f2bf(a0.x), f2bf(a0.y), f2bf(a0.z), f2bf(a0.w) };
            s4v v1 = { f2bf(a1.x), f2bf(a1.y), f2bf(a1.z), f2bf(a1.w) };
            s4v v2 = { f2bf(a2.x), f2bf(a2.y), f2bf(a2.z), f2bf(a2.w) };
            s4v v3 = { f2bf(a3.x), f2bf(a3.y), f2bf(a3.z), f2bf(a3.w) };
            *(s4v*)&As[sm * 68 + skq + 0]  = v0;
            *(s4v*)&As[sm * 68 + skq + 4]  = v1;
            *(s4v*)&As[sm * 68 + skq + 8]  = v2;
            *(s4v*)&As[sm * 68 + skq + 12] = v3;
            s4v u0 = { b01[0], b01[1], b01[2], b01[3] };
            s4v u1 = { b01[4], b01[5], b01[6], b01[7] };
            s4v u2 = { b23[0], b23[1], b23[2], b23[3] };
            s4v u3 = { b23[4], b23[5], b23[6], b23[7] };
            *(s4v*)&Bs[sm * 68 + skq + 0]  = u0;
            *(s4v*)&Bs[sm * 68 + skq + 4]  = u1;
            *(s4v*)&Bs[sm * 68 + skq + 8]  = u2;
            *(s4v*)&Bs[sm * 68 + skq + 12] = u3;
        }
        __syncthreads();
        if (kt < 10) {
            pa += 64; pb += 64;
            a0 = *(const float4*)(pa + 0); a1 = *(const float4*)(pa + 4);
            a2 = *(const float4*)(pa + 8); a3 = *(const float4*)(pa + 12);
            b01 = *(const s8v*)(pb);
            b23 = *(const s8v*)(pb + 8);
        }
        #pragma unroll
        for (int kk = 0; kk < 2; ++kk) {
            int aoff = (w * 16 + r) * 68 + kk * 32 + quad * 8;
            s4v alo = *(s4v*)&As[aoff];
            s4v ahi = *(s4v*)&As[aoff + 4];
            s8v af;
            af[0] = alo[0]; af[1] = alo[1]; af[2] = alo[2]; af[3] = alo[3];
            af[4] = ahi[0]; af[5] = ahi[1]; af[6] = ahi[2]; af[7] = ahi[3];
            #pragma unroll
            for (int t = 0; t < 4; ++t) {
                int boff = (t * 16 + r) * 68 + kk * 32 + quad * 8;
                s4v blo = *(s4v*)&Bs[boff];
                s4v bhi = *(s4v*)&Bs[boff + 4];
                s8v bf;
                bf[0] = blo[0]; bf[1] = blo[1]; bf[2] = blo[2]; bf[3] = blo[3];
                bf[4] = bhi[0]; bf[5] = bhi[1]; bf[6] = bhi[2]; bf[7] = bhi[3];
                acc[t] = __builtin_amdgcn_mfma_f32_16x16x32_bf16(af, bf, acc[t], 0, 0, 0);
            }
        }
    }
    #pragma unroll
    for (int t = 0; t < 4; ++t) {
        int colg = colBase + t * 16 + r;
        size_t obase = (size_t)(colg >> 10) * (256 * NKP) + (size_t)(colg & 1023);
        #pragma unroll
        for (int reg = 0; reg < 4; ++reg) {
            int row = rowBase + w * 16 + quad * 4 + reg;
            out[obase + (size_t)row * NKP] = acc[t][reg] + biasf[row];
        }
    }
}

__global__ __launch_bounds__(256) void k4(const unsigned short* __restrict__ T1,
                                          const unsigned short* __restrict__ T2,
                                          const unsigned short* __restrict__ T3,
                                          const unsigned short* __restrict__ T4,
                                          const int* __restrict__ fidx,
                                          unsigned short* __restrict__ Xb,
                                          const float* __restrict__ Mw,
                                          const float* __restrict__ biasf,
                                          float* __restrict__ outD, int* __restrict__ done) {
    __shared__ __align__(16) char smem[17408];
    if (blockIdx.x < 4096) {
        sample_role(T1, T2, T3, T4, fidx, Xb, smem);
        rel_add(done + 64);
    } else {
        acq_wait(done + 64, 4096);
        gemm_role(Mw, Xb, biasf, outD, blockIdx.x - 4096, smem);
    }
}

// ================= launch =================
extern "C" void kernel_launch(void* const* d_in, const int* in_sizes, int n_in,
                              void* d_out, int out_size, void* d_ws, size_t ws_size,
                              hipStream_t stream) {
    const float* scores  = (const float*)d_in[0];
    const float* d1      = (const float*)d_in[1];
    const float* d2      = (const float*)d_in[2];
    const float* cDa     = (const float*)d_in[3];
    const float* d4      = (const float*)d_in[4];
    const float* lin0_w  = (const float*)d_in[5];
    const float* lin0_b  = (const float*)d_in[6];
    const float* lin1_w  = (const float*)d_in[7];
    const float* lin1_b  = (const float*)d_in[8];
    const float* lin2_w  = (const float*)d_in[9];
    const float* lin2_b  = (const float*)d_in[10];
    const float* merge_w = (const float*)d_in[11];
    const float* merge_b = (const float*)d_in[12];
    float* out = (float*)d_out;

    char* ws = (char*)d_ws;
    unsigned char* M0         = (unsigned char*)ws;                   // 1,228,800
    unsigned char* M1         = (unsigned char*)(ws + 1228800);       // 1,228,800
    unsigned short* Xb        = (unsigned short*)(ws + 2457600);      // 5,767,168
    unsigned long long* cand  = (unsigned long long*)(ws + 8224768);  // 524,288
    int* cnt                  = (int*)(ws + 8749056);                 // 1,024
    int* done                 = (int*)(ws + 8750080);                 // 256
    int* fidx                 = (int*)(ws + 8750336);                 // 16,384
    float* Mw                 = (float*)(ws + 8766720);               // 720,896
    float* biasf              = (float*)(ws + 9487616);               // 1,024
    unsigned short* T1        = (unsigned short*)(ws + 9488640);      // 39,321,600
    unsigned short* T2        = (unsigned short*)(ws + 48810240);     // 19,660,800
    unsigned short* T3        = (unsigned short*)(ws + 68471040);     //  9,830,400
    unsigned short* T4        = (unsigned short*)(ws + 78301440);     //  2,457,600 -> 80,759,040

    k1<<<11985, 256, 0, stream>>>(merge_w, merge_b, lin0_w, lin0_b, lin1_w, lin1_b,
                                  lin2_w, lin2_b, scores, d1, d2, cDa, d4,
                                  Mw, biasf, cnt, done, M0, T1, T2, T3, T4);
    k2<<<1200, 256, 0, stream>>>(scores, M0, M1);
    k3<<<1204, 256, 0, stream>>>(scores, M1, cand, cnt, done, out, fidx);
    k4<<<4352, 256, 0, stream>>>(T1, T2, T3, T4, fidx, Xb, Mw, biasf,
                                 out + B * NKP * 3, done);
}